// Round 6
// baseline (2185.503 us; speedup 1.0000x reference)
//
#include <hip/hip_runtime.h>

#define SQ 65536
#define BSEG 256
#define NSEG (SQ / BSEG)
#define NEGV (-10000.0f)
#define PADV (-1.0e30f)

// ---- Tier-1 ws layout (featT + deferred-argmax batched trace) ----
// FEATT: [8][SQ] f32 = 2 MB ; TRACE: [SQ/4][8][4] f32 = 2 MB ; BP: SQ*8 = 512 KB
#define FT_OFF    0u
#define T1_TRACE  ((unsigned)(8u * SQ * 4u))
#define T1_BP     (T1_TRACE + (unsigned)SQ * 32u)
#define T1_BEST   (T1_BP + (unsigned)SQ * 8u)
#define T1_MAPS   (T1_BEST + 32u)
#define T1_E      (T1_MAPS + (unsigned)NSEG * 8u)
#define WS1       ((size_t)(T1_E + NSEG + 64))

// ---- Tier-2 ws layout (R5: no featT, dump ring) ----
#define T2_TRACE  0u
#define T2_DUMP   ((unsigned)SQ * 32u)
#define T2_BP     (T2_DUMP + 4096u)
#define T2_BEST   (T2_BP + (unsigned)SQ * 8u)
#define T2_MAPS   (T2_BEST + 32u)
#define T2_E      (T2_MAPS + (unsigned)NSEG * 8u)
#define WS2       ((size_t)(T2_E + NSEG + 64))

// ---- Tier-3 (old) ws layout ----
#define OBP_OFF   0u
#define OBEST_OFF ((unsigned)SQ * 8u)
#define OMAPS_OFF (OBEST_OFF + 32u)
#define OE_OFF    (OMAPS_OFF + (unsigned)NSEG * 8u)

__device__ __forceinline__ float rl(float v, int l) {
  return __int_as_float(__builtin_amdgcn_readlane(__float_as_int(v), l));
}

template <int K>
__device__ __forceinline__ float ror16(float v) {
  return __int_as_float(
      __builtin_amdgcn_update_dpp(0, __float_as_int(v), 0x120 + K, 0xF, 0xF, true));
}
template <int K>
__device__ __forceinline__ int ror16i(int v) {
  return __builtin_amdgcn_update_dpp(0, v, 0x120 + K, 0xF, 0xF, true);
}

// ================== feat transpose: featT[r][t] = feats[t*6+r] ==================
__global__ __launch_bounds__(256)
void feat_tr(const float* __restrict__ feats, unsigned char* __restrict__ ws) {
  float* ft = (float*)(ws + FT_OFF);
  // write-coalesced: index over [r][t]
  int idx = blockIdx.x * 256 + threadIdx.x;           // 0 .. 6*SQ-1
  const int r = idx >> 16;                            // SQ = 65536
  const int t = idx & (SQ - 1);
  ft[(unsigned)r * SQ + (unsigned)t] = feats[(unsigned)t * 6u + (unsigned)r];
}

// ================== Tier-1 forward: DPP, featT dwordx4 loads, masked stores ==================
__global__ __launch_bounds__(64, 1)
void viterbi_fwd_dpp3(const float* __restrict__ trans, unsigned char* __restrict__ ws) {
  const int lane = threadIdx.x & 63;
  const int r = lane & 7;
  const int row = r < 6 ? r : 5;  // lanes 6,7 (mod 8) replicate tag 5

  // Probe DPP row_ror direction (HW convention safe)
  int w = ror16i<1>(lane & 15);
  const int dir = (__builtin_amdgcn_readfirstlane(w) == 1) ? 1 : -1;

  // TT[k] pairs with the value arriving via ror16<k>: fv of tag (r + dir*k) & 7
  float TT[8];
#pragma unroll
  for (int k = 0; k < 8; ++k) {
    int p = (r + dir * k) & 7;
    TT[k] = (p < 6) ? trans[row * 6 + p] : PADV;
  }

  const float* fp = (const float*)(ws + FT_OFF) + (unsigned)row * SQ;  // per-lane feat row
  float nfv = (row == 4) ? 0.0f : NEGV;  // init fv (START=4 is 0)
  unsigned voff = T1_TRACE + (unsigned)lane * 16u;   // only lanes 0-7 store

  float4 fq[8];  // 32-step prefetch
#pragma unroll
  for (int b = 0; b < 8; ++b) fq[b] = *(const float4*)(fp + b * 4);

  auto step = [&](float ft) {
    float d1 = ror16<1>(nfv), d2 = ror16<2>(nfv), d3 = ror16<3>(nfv), d4 = ror16<4>(nfv),
          d5 = ror16<5>(nfv), d6 = ror16<6>(nfv), d7 = ror16<7>(nfv);
    float s0 = nfv + TT[0], s1 = d1 + TT[1], s2 = d2 + TT[2], s3 = d3 + TT[3],
          s4 = d4 + TT[4], s5 = d5 + TT[5], s6 = d6 + TT[6], s7 = d7 + TT[7];
    float A = fmaxf(fmaxf(s0, s1), s2);   // v_max3
    float B = fmaxf(fmaxf(s3, s4), s5);   // v_max3
    float C = fmaxf(s6, s7);
    float M = fmaxf(fmaxf(A, B), C);      // max reassociation is exact
    nfv = M + ft;                         // reference add order: max + feat
  };

  for (int blk = 0; blk < SQ / 32 - 1; ++blk) {
    const float* nextp = fp + blk * 32 + 32;
#pragma unroll
    for (int b = 0; b < 8; ++b) {
      float4 f = fq[b];
      step(f.x); float b0 = nfv;
      step(f.y); float b1 = nfv;
      step(f.z); float b2 = nfv;
      step(f.w); float b3 = nfv;
      fq[b] = *(const float4*)(nextp + b * 4);
      if (lane < 8) *(float4*)(ws + voff) = make_float4(b0, b1, b2, b3);
      voff += 128u;
    }
  }
  {  // last 32 steps: no reload
#pragma unroll
    for (int b = 0; b < 8; ++b) {
      float4 f = fq[b];
      step(f.x); float b0 = nfv;
      step(f.y); float b1 = nfv;
      step(f.z); float b2 = nfv;
      step(f.w); float b3 = nfv;
      if (lane < 8) *(float4*)(ws + voff) = make_float4(b0, b1, b2, b3);
      voff += 128u;
    }
  }
}

// ================== Tier-2 forward (R5): direct feats, dump-ring stores ==================
__global__ __launch_bounds__(64, 1)
void viterbi_fwd_dpp2(const float* __restrict__ feats, const float* __restrict__ trans,
                      unsigned char* __restrict__ ws) {
  const int lane = threadIdx.x & 63;
  const int r = lane & 7;
  const int row = r < 6 ? r : 5;
  int w = ror16i<1>(lane & 15);
  const int dir = (__builtin_amdgcn_readfirstlane(w) == 1) ? 1 : -1;
  float TT[8];
#pragma unroll
  for (int k = 0; k < 8; ++k) {
    int p = (r + dir * k) & 7;
    TT[k] = (p < 6) ? trans[row * 6 + p] : PADV;
  }
  const float* fp = feats + row;
  float nfv = (row == 4) ? 0.0f : NEGV;
  unsigned voff = (lane < 8) ? (T2_TRACE + (unsigned)lane * 16u)
                             : (T2_DUMP + (unsigned)lane * 16u);
  const unsigned vstep = (lane < 8) ? 128u : 0u;
  float fq[16];
#pragma unroll
  for (int i = 0; i < 16; ++i) fq[i] = fp[i * 6];
  auto step = [&](float ft) {
    float d1 = ror16<1>(nfv), d2 = ror16<2>(nfv), d3 = ror16<3>(nfv), d4 = ror16<4>(nfv),
          d5 = ror16<5>(nfv), d6 = ror16<6>(nfv), d7 = ror16<7>(nfv);
    float s0 = nfv + TT[0], s1 = d1 + TT[1], s2 = d2 + TT[2], s3 = d3 + TT[3],
          s4 = d4 + TT[4], s5 = d5 + TT[5], s6 = d6 + TT[6], s7 = d7 + TT[7];
    float A = fmaxf(fmaxf(s0, s1), s2);
    float B = fmaxf(fmaxf(s3, s4), s5);
    float C = fmaxf(s6, s7);
    float M = fmaxf(fmaxf(A, B), C);
    nfv = M + ft;
  };
  for (int blk = 0; blk < SQ / 16 - 1; ++blk) {
    const int t = blk * 16;
#pragma unroll
    for (int b = 0; b < 4; ++b) {
      float b0, b1, b2, b3;
      step(fq[b * 4 + 0]); b0 = nfv; fq[b * 4 + 0] = fp[(t + b * 4 + 0 + 16) * 6];
      step(fq[b * 4 + 1]); b1 = nfv; fq[b * 4 + 1] = fp[(t + b * 4 + 1 + 16) * 6];
      step(fq[b * 4 + 2]); b2 = nfv; fq[b * 4 + 2] = fp[(t + b * 4 + 2 + 16) * 6];
      step(fq[b * 4 + 3]); b3 = nfv; fq[b * 4 + 3] = fp[(t + b * 4 + 3 + 16) * 6];
      *(float4*)(ws + voff) = make_float4(b0, b1, b2, b3);
      voff += vstep;
    }
  }
  {
#pragma unroll
    for (int b = 0; b < 4; ++b) {
      float b0, b1, b2, b3;
      step(fq[b * 4 + 0]); b0 = nfv;
      step(fq[b * 4 + 1]); b1 = nfv;
      step(fq[b * 4 + 2]); b2 = nfv;
      step(fq[b * 4 + 3]); b3 = nfv;
      *(float4*)(ws + voff) = make_float4(b0, b1, b2, b3);
      voff += vstep;
    }
  }
}

// ================== Parallel backpointer extraction (bit-exact recompute) ==================
__global__ __launch_bounds__(256)
void bp_kernel(const float* __restrict__ trans, unsigned char* __restrict__ ws,
               unsigned trace_off, unsigned bp_off) {
  const int t = blockIdx.x * 256 + threadIdx.x;
  float fv0, fv1, fv2, fv3, fv4, fv5;
  if (t == 0) {
    fv0 = NEGV; fv1 = NEGV; fv2 = NEGV; fv3 = NEGV; fv4 = 0.0f; fv5 = NEGV;
  } else {
    const int u = t - 1;  // fv after step u; layout [u/4][8 lanes][4]
    const float* f = (const float*)(ws + trace_off) + (unsigned)(u >> 2) * 32u + (unsigned)(u & 3);
    fv0 = f[0]; fv1 = f[4]; fv2 = f[8]; fv3 = f[12]; fv4 = f[16]; fv5 = f[20];
  }
  unsigned long long acc = 0;
#pragma unroll
  for (int n = 0; n < 6; ++n) {
    float s0 = fv0 + trans[n * 6 + 0];
    float s1 = fv1 + trans[n * 6 + 1];
    float s2 = fv2 + trans[n * 6 + 2];
    float s3 = fv3 + trans[n * 6 + 3];
    float s4 = fv4 + trans[n * 6 + 4];
    float s5 = fv5 + trans[n * 6 + 5];
    float m = fmaxf(fmaxf(fmaxf(s0, s1), s2), fmaxf(fmaxf(s3, s4), s5));
    int idx = 5;
    idx = (s4 >= m) ? 4 : idx;
    idx = (s3 >= m) ? 3 : idx;
    idx = (s2 >= m) ? 2 : idx;
    idx = (s1 >= m) ? 1 : idx;
    idx = (s0 >= m) ? 0 : idx;  // numpy first-index tie rule
    acc |= (unsigned long long)idx << (8 * n);
  }
  ((unsigned long long*)(ws + bp_off))[t] = acc;
}

// ================== Tier-3 forward (fallback) ==================
__global__ __launch_bounds__(64, 1)
void viterbi_fwd_old(const float* __restrict__ feats, const float* __restrict__ trans,
                     float* __restrict__ out, unsigned char* __restrict__ ws) {
  const int lane = threadIdx.x;
  if (lane >= 6) return;
  const float T0 = trans[lane * 6 + 0], T1 = trans[lane * 6 + 1], T2 = trans[lane * 6 + 2],
              T3 = trans[lane * 6 + 3], T4 = trans[lane * 6 + 4], T5 = trans[lane * 6 + 5];
  float fv0 = NEGV, fv1 = NEGV, fv2 = NEGV, fv3 = NEGV, fv4 = 0.0f, fv5 = NEGV;
  unsigned char* bpb = ws + OBP_OFF + lane;
  const float* fp = feats + lane;
  float fq[16];
#pragma unroll
  for (int i = 0; i < 16; ++i) fq[i] = fp[i * 6];
  auto step = [&](float ft, int tt) {
    float sc0 = fv0 + T0, sc1 = fv1 + T1, sc2 = fv2 + T2;
    float sc3 = fv3 + T3, sc4 = fv4 + T4, sc5 = fv5 + T5;
    float m = fmaxf(fmaxf(fmaxf(sc0, sc1), sc2), fmaxf(fmaxf(sc3, sc4), sc5));
    int idx = 5;
    idx = (sc4 >= m) ? 4 : idx;
    idx = (sc3 >= m) ? 3 : idx;
    idx = (sc2 >= m) ? 2 : idx;
    idx = (sc1 >= m) ? 1 : idx;
    idx = (sc0 >= m) ? 0 : idx;
    bpb[(unsigned)tt * 8u] = (unsigned char)idx;
    float nfv = m + ft;
    fv0 = rl(nfv, 0); fv1 = rl(nfv, 1); fv2 = rl(nfv, 2);
    fv3 = rl(nfv, 3); fv4 = rl(nfv, 4); fv5 = rl(nfv, 5);
  };
  for (int blk = 0; blk < SQ / 16 - 1; ++blk) {
    const int t = blk * 16;
#pragma unroll
    for (int i = 0; i < 16; ++i) { step(fq[i], t + i); fq[i] = fp[(t + i + 16) * 6]; }
  }
  { const int t = SQ - 16;
#pragma unroll
    for (int i = 0; i < 16; ++i) step(fq[i], t + i); }
  const float q0 = trans[30], q1 = trans[31], q2 = trans[32],
              q3 = trans[33], q4 = trans[34], q5 = trans[35];
  float tv0 = fv0 + q0, tv1 = fv1 + q1, tv2 = fv2 + q2;
  float tv3 = fv3 + q3, tv4 = fv4 + q4, tv5 = fv5 + q5;
  float bm = tv0; int bi = 0;
  if (tv1 > bm) { bm = tv1; bi = 1; }
  if (tv2 > bm) { bm = tv2; bi = 2; }
  if (tv3 > bm) { bm = tv3; bi = 3; }
  if (tv4 > bm) { bm = tv4; bi = 4; }
  if (tv5 > bm) { bm = tv5; bi = 5; }
  if (lane == 0) { out[0] = bm; *(unsigned*)(ws + OBEST_OFF) = (unsigned)bi; }
}

// ================== Backtrack phases ==================
__global__ __launch_bounds__(64, 1)
void bt_maps(unsigned char* __restrict__ ws, unsigned bp_off, unsigned maps_off) {
  const int s = blockIdx.x;
  const int lane = threadIdx.x;
  int x = lane < 6 ? lane : 5;
  const unsigned long long* g = (const unsigned long long*)(ws + bp_off);
  const int lo = s * BSEG + 1;
  const int hi = (s == NSEG - 1) ? (SQ - 1) : (s + 1) * BSEG;
#pragma unroll 8
  for (int j = hi; j >= lo; --j) {
    unsigned long long w = g[j];
    x = (int)((w >> (x * 8)) & 7ull);
  }
  if (lane < 6) ws[maps_off + (unsigned)s * 8u + (unsigned)lane] = (unsigned char)x;
}

__global__ __launch_bounds__(64, 1)
void bt_chain(const float* __restrict__ trans, float* __restrict__ out,
              unsigned char* __restrict__ ws, unsigned trace_off, unsigned best_off,
              unsigned maps_off, unsigned e_off, int do_terminal) {
  __shared__ unsigned char ml[NSEG * 8];
  const unsigned* src = (const unsigned*)(ws + maps_off);
  unsigned* dstw = (unsigned*)ml;
  for (int i = threadIdx.x; i < NSEG * 2; i += 64) dstw[i] = src[i];
  __syncthreads();
  if (threadIdx.x == 0) {
    if (do_terminal) {
      const int u = SQ - 1;
      const float* f = (const float*)(ws + trace_off) + (unsigned)(u >> 2) * 32u + (unsigned)(u & 3);
      float bm = f[0] + trans[30]; int bi = 0;
      float tv;
      tv = f[4]  + trans[31]; if (tv > bm) { bm = tv; bi = 1; }
      tv = f[8]  + trans[32]; if (tv > bm) { bm = tv; bi = 2; }
      tv = f[12] + trans[33]; if (tv > bm) { bm = tv; bi = 3; }
      tv = f[16] + trans[34]; if (tv > bm) { bm = tv; bi = 4; }
      tv = f[20] + trans[35]; if (tv > bm) { bm = tv; bi = 5; }
      out[0] = bm;
      *(unsigned*)(ws + best_off) = (unsigned)bi;
    }
    int x = (int)*(const unsigned*)(ws + best_off);
    for (int s = NSEG - 1; s >= 1; --s) {
      x = ml[s * 8 + x];
      ws[e_off + (unsigned)s] = (unsigned char)x;
    }
  }
}

__global__ __launch_bounds__(64, 1)
void bt_emit(const unsigned char* __restrict__ ws, float* __restrict__ out,
             unsigned bp_off, unsigned best_off, unsigned e_off) {
  const int s = blockIdx.x;
  if (threadIdx.x != 0) return;
  const unsigned long long* g = (const unsigned long long*)(ws + bp_off);
  int x, hi;
  const int lo = s * BSEG + 1;
  if (s == NSEG - 1) {
    x = (int)*(const unsigned*)(ws + best_off);
    out[1 + (SQ - 1)] = (float)x;
    hi = SQ - 1;
  } else {
    x = ws[e_off + (unsigned)(s + 1)];
    hi = (s + 1) * BSEG;
  }
#pragma unroll 8
  for (int j = hi; j >= lo; --j) {
    unsigned long long w = g[j];
    x = (int)((w >> (x * 8)) & 7ull);
    out[j] = (float)x;
  }
}

extern "C" void kernel_launch(void* const* d_in, const int* in_sizes, int n_in,
                              void* d_out, int out_size, void* d_ws, size_t ws_size,
                              hipStream_t stream) {
  const float* feats = (const float*)d_in[0];
  const float* trans = (const float*)d_in[1];
  float* out = (float*)d_out;
  unsigned char* ws = (unsigned char*)d_ws;

  if (ws_size >= WS1) {
    feat_tr<<<6 * SQ / 256, 256, 0, stream>>>(feats, ws);
    viterbi_fwd_dpp3<<<1, 64, 0, stream>>>(trans, ws);
    bp_kernel<<<NSEG, 256, 0, stream>>>(trans, ws, T1_TRACE, T1_BP);
    bt_maps<<<NSEG, 64, 0, stream>>>(ws, T1_BP, T1_MAPS);
    bt_chain<<<1, 64, 0, stream>>>(trans, out, ws, T1_TRACE, T1_BEST, T1_MAPS, T1_E, 1);
    bt_emit<<<NSEG, 64, 0, stream>>>(ws, out, T1_BP, T1_BEST, T1_E);
  } else if (ws_size >= WS2) {
    viterbi_fwd_dpp2<<<1, 64, 0, stream>>>(feats, trans, ws);
    bp_kernel<<<NSEG, 256, 0, stream>>>(trans, ws, T2_TRACE, T2_BP);
    bt_maps<<<NSEG, 64, 0, stream>>>(ws, T2_BP, T2_MAPS);
    bt_chain<<<1, 64, 0, stream>>>(trans, out, ws, T2_TRACE, T2_BEST, T2_MAPS, T2_E, 1);
    bt_emit<<<NSEG, 64, 0, stream>>>(ws, out, T2_BP, T2_BEST, T2_E);
  } else {
    viterbi_fwd_old<<<1, 64, 0, stream>>>(feats, trans, out, ws);
    bt_maps<<<NSEG, 64, 0, stream>>>(ws, OBP_OFF, OMAPS_OFF);
    bt_chain<<<1, 64, 0, stream>>>(trans, out, ws, 0u, OBEST_OFF, OMAPS_OFF, OE_OFF, 0);
    bt_emit<<<NSEG, 64, 0, stream>>>(ws, out, OBP_OFF, OBEST_OFF, OE_OFF);
  }
}

// Round 8
// 2156.432 us; speedup vs baseline: 1.0135x; 1.0135x over previous
//
#include <hip/hip_runtime.h>

#define SQ 65536
#define BSEG 256
#define NSEG (SQ / BSEG)
#define NEGV (-10000.0f)
#define PADV (-1.0e30f)

// ---- Tier-1 ws layout (featT + deferred-argmax batched trace) ----
#define FT_OFF    0u
#define T1_TRACE  ((unsigned)(8u * SQ * 4u))
#define T1_BP     (T1_TRACE + (unsigned)SQ * 32u)
#define T1_BEST   (T1_BP + (unsigned)SQ * 8u)
#define T1_MAPS   (T1_BEST + 32u)
#define T1_E      (T1_MAPS + (unsigned)NSEG * 8u)
#define WS1       ((size_t)(T1_E + NSEG + 64))

// ---- Tier-2 ws layout (R5: no featT, dump ring) ----
#define T2_TRACE  0u
#define T2_DUMP   ((unsigned)SQ * 32u)
#define T2_BP     (T2_DUMP + 4096u)
#define T2_BEST   (T2_BP + (unsigned)SQ * 8u)
#define T2_MAPS   (T2_BEST + 32u)
#define T2_E      (T2_MAPS + (unsigned)NSEG * 8u)
#define WS2       ((size_t)(T2_E + NSEG + 64))

// ---- Tier-3 (old) ws layout ----
#define OBP_OFF   0u
#define OBEST_OFF ((unsigned)SQ * 8u)
#define OMAPS_OFF (OBEST_OFF + 32u)
#define OE_OFF    (OMAPS_OFF + (unsigned)NSEG * 8u)

__device__ __forceinline__ float rl(float v, int l) {
  return __int_as_float(__builtin_amdgcn_readlane(__float_as_int(v), l));
}

template <int K>
__device__ __forceinline__ float ror16(float v) {
  return __int_as_float(
      __builtin_amdgcn_update_dpp(0, __float_as_int(v), 0x120 + K, 0xF, 0xF, true));
}
template <int K>
__device__ __forceinline__ int ror16i(int v) {
  return __builtin_amdgcn_update_dpp(0, v, 0x120 + K, 0xF, 0xF, true);
}

// ================== feat transpose: featT[r][t] = feats[t*6+r] ==================
__global__ __launch_bounds__(256)
void feat_tr(const float* __restrict__ feats, unsigned char* __restrict__ ws) {
  float* ft = (float*)(ws + FT_OFF);
  int idx = blockIdx.x * 256 + threadIdx.x;           // 0 .. 6*SQ-1
  const int r = idx >> 16;                            // SQ = 65536
  const int t = idx & (SQ - 1);
  ft[(unsigned)r * SQ + (unsigned)t] = feats[(unsigned)t * 6u + (unsigned)r];
}

// ================== Tier-1 forward: fused v_add_f32_dpp step (13 insts) ==================
__global__ __launch_bounds__(64, 1)
void viterbi_fwd_dpp4(const float* __restrict__ trans, unsigned char* __restrict__ ws) {
  const int lane = threadIdx.x & 63;
  const int r = lane & 7;
  const int row = r < 6 ? r : 5;  // lanes 6,7 (mod 8) replicate tag 5

  // Probe DPP row_ror direction (same DPP control as the fused adds)
  int w = ror16i<1>(lane & 15);
  const int dir = (__builtin_amdgcn_readfirstlane(w) == 1) ? 1 : -1;

  // TT[k] pairs with the value arriving via row_ror:k — fv of tag (r + dir*k) & 7
  float t0, t1, t2, t3, t4, t5, t6, t7;
  {
    float tmp[8];
#pragma unroll
    for (int k = 0; k < 8; ++k) {
      int p = (r + dir * k) & 7;
      tmp[k] = (p < 6) ? trans[row * 6 + p] : PADV;
    }
    t0 = tmp[0]; t1 = tmp[1]; t2 = tmp[2]; t3 = tmp[3];
    t4 = tmp[4]; t5 = tmp[5]; t6 = tmp[6]; t7 = tmp[7];
  }

  const float* fp = (const float*)(ws + FT_OFF) + (unsigned)row * SQ;
  float nfv = (row == 4) ? 0.0f : NEGV;  // init fv (START=4 is 0)
  unsigned voff = T1_TRACE + (unsigned)lane * 16u;

  // One step: s_k = ror_k(nfv) + TT[k] (fused DPP adds), M = max tree, out = M + ft.
  // 13 instructions; bit-identical operand order to the reference recursion.
  auto step = [&](float ft_, float nin) -> float {
    float s0, s1, s2, s3, s4, s5, s6, s7, out;
    asm("v_add_f32 %[s0], %[nfv], %[t0]\n\t"
        "v_add_f32_dpp %[s1], %[nfv], %[t1] row_ror:1 row_mask:0xf bank_mask:0xf\n\t"
        "v_add_f32_dpp %[s2], %[nfv], %[t2] row_ror:2 row_mask:0xf bank_mask:0xf\n\t"
        "v_add_f32_dpp %[s3], %[nfv], %[t3] row_ror:3 row_mask:0xf bank_mask:0xf\n\t"
        "v_add_f32_dpp %[s4], %[nfv], %[t4] row_ror:4 row_mask:0xf bank_mask:0xf\n\t"
        "v_add_f32_dpp %[s5], %[nfv], %[t5] row_ror:5 row_mask:0xf bank_mask:0xf\n\t"
        "v_add_f32_dpp %[s6], %[nfv], %[t6] row_ror:6 row_mask:0xf bank_mask:0xf\n\t"
        "v_add_f32_dpp %[s7], %[nfv], %[t7] row_ror:7 row_mask:0xf bank_mask:0xf\n\t"
        "v_max3_f32 %[s0], %[s0], %[s1], %[s2]\n\t"
        "v_max3_f32 %[s3], %[s3], %[s4], %[s5]\n\t"
        "v_max_f32 %[s6], %[s6], %[s7]\n\t"
        "v_max3_f32 %[s0], %[s0], %[s3], %[s6]\n\t"
        "v_add_f32 %[out], %[s0], %[ft]"
        : [s0] "=&v"(s0), [s1] "=&v"(s1), [s2] "=&v"(s2), [s3] "=&v"(s3),
          [s4] "=&v"(s4), [s5] "=&v"(s5), [s6] "=&v"(s6), [s7] "=&v"(s7),
          [out] "=v"(out)
        : [nfv] "v"(nin), [t0] "v"(t0), [t1] "v"(t1), [t2] "v"(t2), [t3] "v"(t3),
          [t4] "v"(t4), [t5] "v"(t5), [t6] "v"(t6), [t7] "v"(t7), [ft] "v"(ft_));
    return out;
  };

  float4 fq[8];  // 32-step prefetch
#pragma unroll
  for (int b = 0; b < 8; ++b) fq[b] = *(const float4*)(fp + b * 4);

  for (int blk = 0; blk < SQ / 32 - 1; ++blk) {
    const float* nextp = fp + blk * 32 + 32;
#pragma unroll
    for (int b = 0; b < 8; ++b) {
      float4 f = fq[b];
      float b0 = step(f.x, nfv);
      float b1 = step(f.y, b0);
      float b2 = step(f.z, b1);
      float b3 = step(f.w, b2);
      nfv = b3;
      fq[b] = *(const float4*)(nextp + b * 4);
      if (lane < 8) *(float4*)(ws + voff) = make_float4(b0, b1, b2, b3);
      voff += 128u;
    }
  }
  {  // last 32 steps: no reload
#pragma unroll
    for (int b = 0; b < 8; ++b) {
      float4 f = fq[b];
      float b0 = step(f.x, nfv);
      float b1 = step(f.y, b0);
      float b2 = step(f.z, b1);
      float b3 = step(f.w, b2);
      nfv = b3;
      if (lane < 8) *(float4*)(ws + voff) = make_float4(b0, b1, b2, b3);
      voff += 128u;
    }
  }
}

// ================== Tier-2 forward (R5): direct feats, dump-ring stores ==================
__global__ __launch_bounds__(64, 1)
void viterbi_fwd_dpp2(const float* __restrict__ feats, const float* __restrict__ trans,
                      unsigned char* __restrict__ ws) {
  const int lane = threadIdx.x & 63;
  const int r = lane & 7;
  const int row = r < 6 ? r : 5;
  int w = ror16i<1>(lane & 15);
  const int dir = (__builtin_amdgcn_readfirstlane(w) == 1) ? 1 : -1;
  float TT[8];
#pragma unroll
  for (int k = 0; k < 8; ++k) {
    int p = (r + dir * k) & 7;
    TT[k] = (p < 6) ? trans[row * 6 + p] : PADV;
  }
  const float* fp = feats + row;
  float nfv = (row == 4) ? 0.0f : NEGV;
  unsigned voff = (lane < 8) ? (T2_TRACE + (unsigned)lane * 16u)
                             : (T2_DUMP + (unsigned)lane * 16u);
  const unsigned vstep = (lane < 8) ? 128u : 0u;
  float fq[16];
#pragma unroll
  for (int i = 0; i < 16; ++i) fq[i] = fp[i * 6];
  auto step = [&](float ft) {
    float d1 = ror16<1>(nfv), d2 = ror16<2>(nfv), d3 = ror16<3>(nfv), d4 = ror16<4>(nfv),
          d5 = ror16<5>(nfv), d6 = ror16<6>(nfv), d7 = ror16<7>(nfv);
    float s0 = nfv + TT[0], s1 = d1 + TT[1], s2 = d2 + TT[2], s3 = d3 + TT[3],
          s4 = d4 + TT[4], s5 = d5 + TT[5], s6 = d6 + TT[6], s7 = d7 + TT[7];
    float A = fmaxf(fmaxf(s0, s1), s2);
    float B = fmaxf(fmaxf(s3, s4), s5);
    float C = fmaxf(s6, s7);
    float M = fmaxf(fmaxf(A, B), C);
    nfv = M + ft;
  };
  for (int blk = 0; blk < SQ / 16 - 1; ++blk) {
    const int t = blk * 16;
#pragma unroll
    for (int b = 0; b < 4; ++b) {
      float b0, b1, b2, b3;
      step(fq[b * 4 + 0]); b0 = nfv; fq[b * 4 + 0] = fp[(t + b * 4 + 0 + 16) * 6];
      step(fq[b * 4 + 1]); b1 = nfv; fq[b * 4 + 1] = fp[(t + b * 4 + 1 + 16) * 6];
      step(fq[b * 4 + 2]); b2 = nfv; fq[b * 4 + 2] = fp[(t + b * 4 + 2 + 16) * 6];
      step(fq[b * 4 + 3]); b3 = nfv; fq[b * 4 + 3] = fp[(t + b * 4 + 3 + 16) * 6];
      *(float4*)(ws + voff) = make_float4(b0, b1, b2, b3);
      voff += vstep;
    }
  }
  {
#pragma unroll
    for (int b = 0; b < 4; ++b) {
      float b0, b1, b2, b3;
      step(fq[b * 4 + 0]); b0 = nfv;
      step(fq[b * 4 + 1]); b1 = nfv;
      step(fq[b * 4 + 2]); b2 = nfv;
      step(fq[b * 4 + 3]); b3 = nfv;
      *(float4*)(ws + voff) = make_float4(b0, b1, b2, b3);
      voff += vstep;
    }
  }
}

// ================== Parallel backpointer extraction (bit-exact recompute) ==================
__global__ __launch_bounds__(256)
void bp_kernel(const float* __restrict__ trans, unsigned char* __restrict__ ws,
               unsigned trace_off, unsigned bp_off) {
  const int t = blockIdx.x * 256 + threadIdx.x;
  float fv0, fv1, fv2, fv3, fv4, fv5;
  if (t == 0) {
    fv0 = NEGV; fv1 = NEGV; fv2 = NEGV; fv3 = NEGV; fv4 = 0.0f; fv5 = NEGV;
  } else {
    const int u = t - 1;  // fv after step u; layout [u/4][8 lanes][4]
    const float* f = (const float*)(ws + trace_off) + (unsigned)(u >> 2) * 32u + (unsigned)(u & 3);
    fv0 = f[0]; fv1 = f[4]; fv2 = f[8]; fv3 = f[12]; fv4 = f[16]; fv5 = f[20];
  }
  unsigned long long acc = 0;
#pragma unroll
  for (int n = 0; n < 6; ++n) {
    float s0 = fv0 + trans[n * 6 + 0];
    float s1 = fv1 + trans[n * 6 + 1];
    float s2 = fv2 + trans[n * 6 + 2];
    float s3 = fv3 + trans[n * 6 + 3];
    float s4 = fv4 + trans[n * 6 + 4];
    float s5 = fv5 + trans[n * 6 + 5];
    float m = fmaxf(fmaxf(fmaxf(s0, s1), s2), fmaxf(fmaxf(s3, s4), s5));
    int idx = 5;
    idx = (s4 >= m) ? 4 : idx;
    idx = (s3 >= m) ? 3 : idx;
    idx = (s2 >= m) ? 2 : idx;
    idx = (s1 >= m) ? 1 : idx;
    idx = (s0 >= m) ? 0 : idx;  // numpy first-index tie rule
    acc |= (unsigned long long)idx << (8 * n);
  }
  ((unsigned long long*)(ws + bp_off))[t] = acc;
}

// ================== Tier-3 forward (fallback) ==================
__global__ __launch_bounds__(64, 1)
void viterbi_fwd_old(const float* __restrict__ feats, const float* __restrict__ trans,
                     float* __restrict__ out, unsigned char* __restrict__ ws) {
  const int lane = threadIdx.x;
  if (lane >= 6) return;
  const float T0 = trans[lane * 6 + 0], T1 = trans[lane * 6 + 1], T2 = trans[lane * 6 + 2],
              T3 = trans[lane * 6 + 3], T4 = trans[lane * 6 + 4], T5 = trans[lane * 6 + 5];
  float fv0 = NEGV, fv1 = NEGV, fv2 = NEGV, fv3 = NEGV, fv4 = 0.0f, fv5 = NEGV;
  unsigned char* bpb = ws + OBP_OFF + lane;
  const float* fp = feats + lane;
  float fq[16];
#pragma unroll
  for (int i = 0; i < 16; ++i) fq[i] = fp[i * 6];
  auto step = [&](float ft, int tt) {
    float sc0 = fv0 + T0, sc1 = fv1 + T1, sc2 = fv2 + T2;
    float sc3 = fv3 + T3, sc4 = fv4 + T4, sc5 = fv5 + T5;
    float m = fmaxf(fmaxf(fmaxf(sc0, sc1), sc2), fmaxf(fmaxf(sc3, sc4), sc5));
    int idx = 5;
    idx = (sc4 >= m) ? 4 : idx;
    idx = (sc3 >= m) ? 3 : idx;
    idx = (sc2 >= m) ? 2 : idx;
    idx = (sc1 >= m) ? 1 : idx;
    idx = (sc0 >= m) ? 0 : idx;
    bpb[(unsigned)tt * 8u] = (unsigned char)idx;
    float nfv = m + ft;
    fv0 = rl(nfv, 0); fv1 = rl(nfv, 1); fv2 = rl(nfv, 2);
    fv3 = rl(nfv, 3); fv4 = rl(nfv, 4); fv5 = rl(nfv, 5);
  };
  for (int blk = 0; blk < SQ / 16 - 1; ++blk) {
    const int t = blk * 16;
#pragma unroll
    for (int i = 0; i < 16; ++i) { step(fq[i], t + i); fq[i] = fp[(t + i + 16) * 6]; }
  }
  { const int t = SQ - 16;
#pragma unroll
    for (int i = 0; i < 16; ++i) step(fq[i], t + i); }
  const float q0 = trans[30], q1 = trans[31], q2 = trans[32],
              q3 = trans[33], q4 = trans[34], q5 = trans[35];
  float tv0 = fv0 + q0, tv1 = fv1 + q1, tv2 = fv2 + q2;
  float tv3 = fv3 + q3, tv4 = fv4 + q4, tv5 = fv5 + q5;
  float bm = tv0; int bi = 0;
  if (tv1 > bm) { bm = tv1; bi = 1; }
  if (tv2 > bm) { bm = tv2; bi = 2; }
  if (tv3 > bm) { bm = tv3; bi = 3; }
  if (tv4 > bm) { bm = tv4; bi = 4; }
  if (tv5 > bm) { bm = tv5; bi = 5; }
  if (lane == 0) { out[0] = bm; *(unsigned*)(ws + OBEST_OFF) = (unsigned)bi; }
}

// ================== Backtrack phases ==================
__global__ __launch_bounds__(64, 1)
void bt_maps(unsigned char* __restrict__ ws, unsigned bp_off, unsigned maps_off) {
  const int s = blockIdx.x;
  const int lane = threadIdx.x;
  int x = lane < 6 ? lane : 5;
  const unsigned long long* g = (const unsigned long long*)(ws + bp_off);
  const int lo = s * BSEG + 1;
  const int hi = (s == NSEG - 1) ? (SQ - 1) : (s + 1) * BSEG;
#pragma unroll 8
  for (int j = hi; j >= lo; --j) {
    unsigned long long w = g[j];
    x = (int)((w >> (x * 8)) & 7ull);
  }
  if (lane < 6) ws[maps_off + (unsigned)s * 8u + (unsigned)lane] = (unsigned char)x;
}

__global__ __launch_bounds__(64, 1)
void bt_chain(const float* __restrict__ trans, float* __restrict__ out,
              unsigned char* __restrict__ ws, unsigned trace_off, unsigned best_off,
              unsigned maps_off, unsigned e_off, int do_terminal) {
  __shared__ unsigned char ml[NSEG * 8];
  const unsigned* src = (const unsigned*)(ws + maps_off);
  unsigned* dstw = (unsigned*)ml;
  for (int i = threadIdx.x; i < NSEG * 2; i += 64) dstw[i] = src[i];
  __syncthreads();
  if (threadIdx.x == 0) {
    if (do_terminal) {
      const int u = SQ - 1;
      const float* f = (const float*)(ws + trace_off) + (unsigned)(u >> 2) * 32u + (unsigned)(u & 3);
      float bm = f[0] + trans[30]; int bi = 0;
      float tv;
      tv = f[4]  + trans[31]; if (tv > bm) { bm = tv; bi = 1; }
      tv = f[8]  + trans[32]; if (tv > bm) { bm = tv; bi = 2; }
      tv = f[12] + trans[33]; if (tv > bm) { bm = tv; bi = 3; }
      tv = f[16] + trans[34]; if (tv > bm) { bm = tv; bi = 4; }
      tv = f[20] + trans[35]; if (tv > bm) { bm = tv; bi = 5; }
      out[0] = bm;
      *(unsigned*)(ws + best_off) = (unsigned)bi;
    }
    int x = (int)*(const unsigned*)(ws + best_off);
    for (int s = NSEG - 1; s >= 1; --s) {
      x = ml[s * 8 + x];
      ws[e_off + (unsigned)s] = (unsigned char)x;
    }
  }
}

__global__ __launch_bounds__(64, 1)
void bt_emit(const unsigned char* __restrict__ ws, float* __restrict__ out,
             unsigned bp_off, unsigned best_off, unsigned e_off) {
  const int s = blockIdx.x;
  if (threadIdx.x != 0) return;
  const unsigned long long* g = (const unsigned long long*)(ws + bp_off);
  int x, hi;
  const int lo = s * BSEG + 1;
  if (s == NSEG - 1) {
    x = (int)*(const unsigned*)(ws + best_off);
    out[1 + (SQ - 1)] = (float)x;
    hi = SQ - 1;
  } else {
    x = ws[e_off + (unsigned)(s + 1)];
    hi = (s + 1) * BSEG;
  }
#pragma unroll 8
  for (int j = hi; j >= lo; --j) {
    unsigned long long w = g[j];
    x = (int)((w >> (x * 8)) & 7ull);
    out[j] = (float)x;
  }
}

extern "C" void kernel_launch(void* const* d_in, const int* in_sizes, int n_in,
                              void* d_out, int out_size, void* d_ws, size_t ws_size,
                              hipStream_t stream) {
  const float* feats = (const float*)d_in[0];
  const float* trans = (const float*)d_in[1];
  float* out = (float*)d_out;
  unsigned char* ws = (unsigned char*)d_ws;

  if (ws_size >= WS1) {
    feat_tr<<<6 * SQ / 256, 256, 0, stream>>>(feats, ws);
    viterbi_fwd_dpp4<<<1, 64, 0, stream>>>(trans, ws);
    bp_kernel<<<NSEG, 256, 0, stream>>>(trans, ws, T1_TRACE, T1_BP);
    bt_maps<<<NSEG, 64, 0, stream>>>(ws, T1_BP, T1_MAPS);
    bt_chain<<<1, 64, 0, stream>>>(trans, out, ws, T1_TRACE, T1_BEST, T1_MAPS, T1_E, 1);
    bt_emit<<<NSEG, 64, 0, stream>>>(ws, out, T1_BP, T1_BEST, T1_E);
  } else if (ws_size >= WS2) {
    viterbi_fwd_dpp2<<<1, 64, 0, stream>>>(feats, trans, ws);
    bp_kernel<<<NSEG, 256, 0, stream>>>(trans, ws, T2_TRACE, T2_BP);
    bt_maps<<<NSEG, 64, 0, stream>>>(ws, T2_BP, T2_MAPS);
    bt_chain<<<1, 64, 0, stream>>>(trans, out, ws, T2_TRACE, T2_BEST, T2_MAPS, T2_E, 1);
    bt_emit<<<NSEG, 64, 0, stream>>>(ws, out, T2_BP, T2_BEST, T2_E);
  } else {
    viterbi_fwd_old<<<1, 64, 0, stream>>>(feats, trans, out, ws);
    bt_maps<<<NSEG, 64, 0, stream>>>(ws, OBP_OFF, OMAPS_OFF);
    bt_chain<<<1, 64, 0, stream>>>(trans, out, ws, 0u, OBEST_OFF, OMAPS_OFF, OE_OFF, 0);
    bt_emit<<<NSEG, 64, 0, stream>>>(ws, out, OBP_OFF, OBEST_OFF, OE_OFF);
  }
}

// Round 9
// 1417.690 us; speedup vs baseline: 1.5416x; 1.5211x over previous
//
#include <hip/hip_runtime.h>

#define SQ 65536
#define BSEG 256
#define NSEG (SQ / BSEG)
#define NEGV (-10000.0f)

// ---- Tier-0 ws layout (4-tag reduced recursion) ----
// FT4: [4][SQ] f32 = 1 MB ; TR4: [SQ/4][4 tags][4 slots] f32 = 1 MB ; BP4: SQ*4 = 256 KB
#define FT4_OFF   0u
#define TR4_OFF   ((unsigned)(4u * SQ * 4u))
#define BP4_OFF   (TR4_OFF + (unsigned)SQ * 16u)
#define B4_BEST   (BP4_OFF + (unsigned)SQ * 4u)
#define B4_MAPS   (B4_BEST + 32u)
#define B4_E      (B4_MAPS + (unsigned)NSEG * 8u)
#define WS0       ((size_t)(B4_E + NSEG + 64))

// ---- Tier-3 (old 6-tag single-kernel) ws layout ----
#define OBP_OFF   0u
#define OBEST_OFF ((unsigned)SQ * 8u)
#define OMAPS_OFF (OBEST_OFF + 32u)
#define OE_OFF    (OMAPS_OFF + (unsigned)NSEG * 8u)

__device__ __forceinline__ float rl(float v, int l) {
  return __int_as_float(__builtin_amdgcn_readlane(__float_as_int(v), l));
}
template <int K>
__device__ __forceinline__ int ror16i(int v) {
  return __builtin_amdgcn_update_dpp(0, v, 0x120 + K, 0xF, 0xF, true);
}

// ================== feat transpose (rows 0..3 only): ft[r][t] = feats[t*6+r] ==================
__global__ __launch_bounds__(256)
void feat_tr4(const float* __restrict__ feats, unsigned char* __restrict__ ws) {
  float* ft = (float*)(ws + FT4_OFF);
  int idx = blockIdx.x * 256 + threadIdx.x;           // 0 .. 4*SQ-1
  const int r = idx >> 16;                            // SQ = 65536
  const int t = idx & (SQ - 1);
  ft[(unsigned)r * SQ + (unsigned)t] = feats[(unsigned)t * 6u + (unsigned)r];
}

// ================== Tier-0 forward: 4-tag, 3 DPP per step ==================
// Tags 4 (START) and 5 (STOP) can never win any max (margin ~1e4): fv[0..3] is
// closed under p in {0..3} with bit-identical values. Step 0 handled specially
// (START dominates): fv1[n] = fl(T[n,4] + f0[n]).
__global__ __launch_bounds__(64, 1)
void viterbi_fwd4(const float* __restrict__ trans, unsigned char* __restrict__ ws) {
  const int lane = threadIdx.x & 63;
  const int r = lane & 3;  // 16 replicas of the 4-tag state

  // Probe DPP row_ror direction (HW convention safe)
  int w = ror16i<1>(lane & 15);
  const int dir = (__builtin_amdgcn_readfirstlane(w) == 1) ? 1 : -1;

  // TT[k] pairs with the value arriving via row_ror:k — fv of tag (r + dir*k) & 3
  float t0, t1, t2, t3;
  {
    float tmp[4];
#pragma unroll
    for (int k = 0; k < 4; ++k) {
      int p = (r + dir * k) & 3;
      tmp[k] = trans[r * 6 + p];
    }
    t0 = tmp[0]; t1 = tmp[1]; t2 = tmp[2]; t3 = tmp[3];
  }

  const float* fp = (const float*)(ws + FT4_OFF) + (unsigned)r * SQ;
  // Special step u=0: fl(0 + T[r,4]) = T[r,4] exact, then + f0[r]
  float nfv = trans[r * 6 + 4] + fp[0];
  unsigned voff = TR4_OFF + (unsigned)lane * 16u;

  // One step: 7 insts, 3 DPP. Bit-identical operand order to the reference.
  auto step = [&](float ft_, float nin) -> float {
    float s0, s1, s2, s3, out;
    asm("v_add_f32 %[s0], %[nfv], %[t0]\n\t"
        "v_add_f32_dpp %[s1], %[nfv], %[t1] row_ror:1 row_mask:0xf bank_mask:0xf\n\t"
        "v_add_f32_dpp %[s2], %[nfv], %[t2] row_ror:2 row_mask:0xf bank_mask:0xf\n\t"
        "v_add_f32_dpp %[s3], %[nfv], %[t3] row_ror:3 row_mask:0xf bank_mask:0xf\n\t"
        "v_max3_f32 %[s0], %[s0], %[s1], %[s2]\n\t"
        "v_max_f32 %[s0], %[s0], %[s3]\n\t"
        "v_add_f32 %[out], %[s0], %[ft]"
        : [s0] "=&v"(s0), [s1] "=&v"(s1), [s2] "=&v"(s2), [s3] "=&v"(s3),
          [out] "=v"(out)
        : [nfv] "v"(nin), [t0] "v"(t0), [t1] "v"(t1), [t2] "v"(t2), [t3] "v"(t3),
          [ft] "v"(ft_));
    return out;
  };

  // Batch 0 (rec 0): slot0 = special fv1; steps u=1,2,3
  {
    float4 f = *(const float4*)(fp + 0);
    float b0 = nfv;
    float b1 = step(f.y, b0);
    float b2 = step(f.z, b1);
    float b3 = step(f.w, b2);
    nfv = b3;
    if (lane < 4) *(float4*)(ws + voff) = make_float4(b0, b1, b2, b3);
    voff += 64u;
  }
  // Main: batches b=1..16376 in 2047 blocks of 8, 32-step prefetch
  float4 fq[8];
#pragma unroll
  for (int i = 0; i < 8; ++i) fq[i] = *(const float4*)(fp + 4 + i * 4);
  for (int blk = 0; blk < 2047; ++blk) {
    const float* nextp = fp + 4 + (blk * 8 + 8) * 4;
#pragma unroll
    for (int i = 0; i < 8; ++i) {
      float4 f = fq[i];
      float b0 = step(f.x, nfv);
      float b1 = step(f.y, b0);
      float b2 = step(f.z, b1);
      float b3 = step(f.w, b2);
      nfv = b3;
      fq[i] = *(const float4*)(nextp + i * 4);  // overrun at end is benign (in-ws)
      if (lane < 4) *(float4*)(ws + voff) = make_float4(b0, b1, b2, b3);
      voff += 64u;
    }
  }
  // Tail: batches 16377..16383 (steps up to u=65535), direct loads
#pragma unroll
  for (int i = 0; i < 7; ++i) {
    float4 f = *(const float4*)(fp + (16377 + i) * 4);
    float b0 = step(f.x, nfv);
    float b1 = step(f.y, b0);
    float b2 = step(f.z, b1);
    float b3 = step(f.w, b2);
    nfv = b3;
    if (lane < 4) *(float4*)(ws + voff) = make_float4(b0, b1, b2, b3);
    voff += 64u;
  }
}

// ================== Parallel 4-tag backpointer extraction (bit-exact recompute) ==================
__global__ __launch_bounds__(256)
void bp4_kernel(const float* __restrict__ trans, unsigned char* __restrict__ ws) {
  const int t = blockIdx.x * 256 + threadIdx.x;
  unsigned acc = 0;
  if (t > 0) {
    const int u = t - 1;  // trace[u] = fv after feat row u; layout [u/4][tag][slot]
    const float* f = (const float*)(ws + TR4_OFF) + (unsigned)(u >> 2) * 16u + (unsigned)(u & 3);
    float fv0 = f[0], fv1 = f[4], fv2 = f[8], fv3 = f[12];
#pragma unroll
    for (int n = 0; n < 4; ++n) {
      float s0 = fv0 + trans[n * 6 + 0];
      float s1 = fv1 + trans[n * 6 + 1];
      float s2 = fv2 + trans[n * 6 + 2];
      float s3 = fv3 + trans[n * 6 + 3];
      float m = fmaxf(fmaxf(s0, s1), fmaxf(s2, s3));
      int idx = 3;
      idx = (s2 >= m) ? 2 : idx;
      idx = (s1 >= m) ? 1 : idx;
      idx = (s0 >= m) ? 0 : idx;  // numpy first-index tie rule; p=4,5 can't win/tie
      acc |= (unsigned)idx << (8 * n);
    }
  }
  ((unsigned*)(ws + BP4_OFF))[t] = acc;  // bp[0] never used by backtrack
}

// ================== Backtrack (4-tag, u32 bp words) ==================
__global__ __launch_bounds__(64, 1)
void bt_maps4(unsigned char* __restrict__ ws) {
  const int s = blockIdx.x;
  const int lane = threadIdx.x;
  int x = lane & 3;
  const unsigned* g = (const unsigned*)(ws + BP4_OFF);
  const int lo = s * BSEG + 1;
  const int hi = (s == NSEG - 1) ? (SQ - 1) : (s + 1) * BSEG;
#pragma unroll 8
  for (int j = hi; j >= lo; --j) {
    unsigned w = g[j];
    x = (int)((w >> (x * 8)) & 0xffu);
  }
  if (lane < 4) ws[B4_MAPS + (unsigned)s * 8u + (unsigned)lane] = (unsigned char)x;
}

__global__ __launch_bounds__(64, 1)
void bt_chain4(const float* __restrict__ trans, float* __restrict__ out,
               unsigned char* __restrict__ ws) {
  __shared__ unsigned char ml[NSEG * 8];
  const unsigned* src = (const unsigned*)(ws + B4_MAPS);
  unsigned* dstw = (unsigned*)ml;
  for (int i = threadIdx.x; i < NSEG * 2; i += 64) dstw[i] = src[i];
  __syncthreads();
  if (threadIdx.x == 0) {
    // terminal: fv[S-1] + trans[STOP]; tags 4,5 lose by ~1e4, argmax over 0..3
    const float* f = (const float*)(ws + TR4_OFF) + 16383u * 16u + 3u;
    float bm = f[0] + trans[30]; int bi = 0;
    float tv;
    tv = f[4]  + trans[31]; if (tv > bm) { bm = tv; bi = 1; }
    tv = f[8]  + trans[32]; if (tv > bm) { bm = tv; bi = 2; }
    tv = f[12] + trans[33]; if (tv > bm) { bm = tv; bi = 3; }
    out[0] = bm;
    *(unsigned*)(ws + B4_BEST) = (unsigned)bi;
    int x = bi;
    for (int s = NSEG - 1; s >= 1; --s) {
      x = ml[s * 8 + x];
      ws[B4_E + (unsigned)s] = (unsigned char)x;
    }
  }
}

__global__ __launch_bounds__(64, 1)
void bt_emit4(const unsigned char* __restrict__ ws, float* __restrict__ out) {
  const int s = blockIdx.x;
  if (threadIdx.x != 0) return;
  const unsigned* g = (const unsigned*)(ws + BP4_OFF);
  int x, hi;
  const int lo = s * BSEG + 1;
  if (s == NSEG - 1) {
    x = (int)*(const unsigned*)(ws + B4_BEST);
    out[1 + (SQ - 1)] = (float)x;
    hi = SQ - 1;
  } else {
    x = ws[B4_E + (unsigned)(s + 1)];
    hi = (s + 1) * BSEG;
  }
#pragma unroll 8
  for (int j = hi; j >= lo; --j) {
    unsigned w = g[j];
    x = (int)((w >> (x * 8)) & 0xffu);
    out[j] = (float)x;
  }
}

// ================== Tier-3 forward (fallback, full 6-tag) ==================
__global__ __launch_bounds__(64, 1)
void viterbi_fwd_old(const float* __restrict__ feats, const float* __restrict__ trans,
                     float* __restrict__ out, unsigned char* __restrict__ ws) {
  const int lane = threadIdx.x;
  if (lane >= 6) return;
  const float T0 = trans[lane * 6 + 0], T1 = trans[lane * 6 + 1], T2 = trans[lane * 6 + 2],
              T3 = trans[lane * 6 + 3], T4 = trans[lane * 6 + 4], T5 = trans[lane * 6 + 5];
  float fv0 = NEGV, fv1 = NEGV, fv2 = NEGV, fv3 = NEGV, fv4 = 0.0f, fv5 = NEGV;
  unsigned char* bpb = ws + OBP_OFF + lane;
  const float* fp = feats + lane;
  float fq[16];
#pragma unroll
  for (int i = 0; i < 16; ++i) fq[i] = fp[i * 6];
  auto step = [&](float ft, int tt) {
    float sc0 = fv0 + T0, sc1 = fv1 + T1, sc2 = fv2 + T2;
    float sc3 = fv3 + T3, sc4 = fv4 + T4, sc5 = fv5 + T5;
    float m = fmaxf(fmaxf(fmaxf(sc0, sc1), sc2), fmaxf(fmaxf(sc3, sc4), sc5));
    int idx = 5;
    idx = (sc4 >= m) ? 4 : idx;
    idx = (sc3 >= m) ? 3 : idx;
    idx = (sc2 >= m) ? 2 : idx;
    idx = (sc1 >= m) ? 1 : idx;
    idx = (sc0 >= m) ? 0 : idx;
    bpb[(unsigned)tt * 8u] = (unsigned char)idx;
    float nfv = m + ft;
    fv0 = rl(nfv, 0); fv1 = rl(nfv, 1); fv2 = rl(nfv, 2);
    fv3 = rl(nfv, 3); fv4 = rl(nfv, 4); fv5 = rl(nfv, 5);
  };
  for (int blk = 0; blk < SQ / 16 - 1; ++blk) {
    const int t = blk * 16;
#pragma unroll
    for (int i = 0; i < 16; ++i) { step(fq[i], t + i); fq[i] = fp[(t + i + 16) * 6]; }
  }
  { const int t = SQ - 16;
#pragma unroll
    for (int i = 0; i < 16; ++i) step(fq[i], t + i); }
  const float q0 = trans[30], q1 = trans[31], q2 = trans[32],
              q3 = trans[33], q4 = trans[34], q5 = trans[35];
  float tv0 = fv0 + q0, tv1 = fv1 + q1, tv2 = fv2 + q2;
  float tv3 = fv3 + q3, tv4 = fv4 + q4, tv5 = fv5 + q5;
  float bm = tv0; int bi = 0;
  if (tv1 > bm) { bm = tv1; bi = 1; }
  if (tv2 > bm) { bm = tv2; bi = 2; }
  if (tv3 > bm) { bm = tv3; bi = 3; }
  if (tv4 > bm) { bm = tv4; bi = 4; }
  if (tv5 > bm) { bm = tv5; bi = 5; }
  if (lane == 0) { out[0] = bm; *(unsigned*)(ws + OBEST_OFF) = (unsigned)bi; }
}

__global__ __launch_bounds__(64, 1)
void bt_maps_o(unsigned char* __restrict__ ws) {
  const int s = blockIdx.x;
  const int lane = threadIdx.x;
  int x = lane < 6 ? lane : 5;
  const unsigned long long* g = (const unsigned long long*)(ws + OBP_OFF);
  const int lo = s * BSEG + 1;
  const int hi = (s == NSEG - 1) ? (SQ - 1) : (s + 1) * BSEG;
#pragma unroll 8
  for (int j = hi; j >= lo; --j) {
    unsigned long long w = g[j];
    x = (int)((w >> (x * 8)) & 7ull);
  }
  if (lane < 6) ws[OMAPS_OFF + (unsigned)s * 8u + (unsigned)lane] = (unsigned char)x;
}

__global__ __launch_bounds__(64, 1)
void bt_chain_o(unsigned char* __restrict__ ws) {
  __shared__ unsigned char ml[NSEG * 8];
  const unsigned* src = (const unsigned*)(ws + OMAPS_OFF);
  unsigned* dstw = (unsigned*)ml;
  for (int i = threadIdx.x; i < NSEG * 2; i += 64) dstw[i] = src[i];
  __syncthreads();
  if (threadIdx.x == 0) {
    int x = (int)*(const unsigned*)(ws + OBEST_OFF);
    for (int s = NSEG - 1; s >= 1; --s) {
      x = ml[s * 8 + x];
      ws[OE_OFF + (unsigned)s] = (unsigned char)x;
    }
  }
}

__global__ __launch_bounds__(64, 1)
void bt_emit_o(const unsigned char* __restrict__ ws, float* __restrict__ out) {
  const int s = blockIdx.x;
  if (threadIdx.x != 0) return;
  const unsigned long long* g = (const unsigned long long*)(ws + OBP_OFF);
  int x, hi;
  const int lo = s * BSEG + 1;
  if (s == NSEG - 1) {
    x = (int)*(const unsigned*)(ws + OBEST_OFF);
    out[1 + (SQ - 1)] = (float)x;
    hi = SQ - 1;
  } else {
    x = ws[OE_OFF + (unsigned)(s + 1)];
    hi = (s + 1) * BSEG;
  }
#pragma unroll 8
  for (int j = hi; j >= lo; --j) {
    unsigned long long w = g[j];
    x = (int)((w >> (x * 8)) & 7ull);
    out[j] = (float)x;
  }
}

extern "C" void kernel_launch(void* const* d_in, const int* in_sizes, int n_in,
                              void* d_out, int out_size, void* d_ws, size_t ws_size,
                              hipStream_t stream) {
  const float* feats = (const float*)d_in[0];
  const float* trans = (const float*)d_in[1];
  float* out = (float*)d_out;
  unsigned char* ws = (unsigned char*)d_ws;

  if (ws_size >= WS0) {
    feat_tr4<<<4 * SQ / 256, 256, 0, stream>>>(feats, ws);
    viterbi_fwd4<<<1, 64, 0, stream>>>(trans, ws);
    bp4_kernel<<<NSEG, 256, 0, stream>>>(trans, ws);
    bt_maps4<<<NSEG, 64, 0, stream>>>(ws);
    bt_chain4<<<1, 64, 0, stream>>>(trans, out, ws);
    bt_emit4<<<NSEG, 64, 0, stream>>>(ws, out);
  } else {
    viterbi_fwd_old<<<1, 64, 0, stream>>>(feats, trans, out, ws);
    bt_maps_o<<<NSEG, 64, 0, stream>>>(ws);
    bt_chain_o<<<1, 64, 0, stream>>>(ws);
    bt_emit_o<<<NSEG, 64, 0, stream>>>(ws, out);
  }
}

// Round 10
// 1413.471 us; speedup vs baseline: 1.5462x; 1.0030x over previous
//
#include <hip/hip_runtime.h>

#define SQ 65536
#define BSEG 256
#define NSEG (SQ / BSEG)
#define NEGV (-10000.0f)

// ---- Tier-0 ws layout (4-tag reduced recursion) ----
// FT4: [4][SQ] f32 = 1 MB ; TR4: [SQ/4][4 tags][4 slots] f32 = 1 MB ; BP4: SQ*4 = 256 KB
#define FT4_OFF   0u
#define TR4_OFF   ((unsigned)(4u * SQ * 4u))
#define BP4_OFF   (TR4_OFF + (unsigned)SQ * 16u)
#define B4_BEST   (BP4_OFF + (unsigned)SQ * 4u)
#define B4_MAPS   (B4_BEST + 32u)
#define B4_E      (B4_MAPS + (unsigned)NSEG * 8u)
#define WS0       ((size_t)(B4_E + NSEG + 64))

// ---- Tier-3 (old 6-tag single-kernel) ws layout ----
#define OBP_OFF   0u
#define OBEST_OFF ((unsigned)SQ * 8u)
#define OMAPS_OFF (OBEST_OFF + 32u)
#define OE_OFF    (OMAPS_OFF + (unsigned)NSEG * 8u)

__device__ __forceinline__ float rl(float v, int l) {
  return __int_as_float(__builtin_amdgcn_readlane(__float_as_int(v), l));
}
// quad_perm rotate-by-K probe helper: ctrl = sum ((i+K)&3) << 2i
__device__ __forceinline__ int qperm1i(int v) {
  return __builtin_amdgcn_update_dpp(0, v, 0x39, 0xF, 0xF, true);  // [1,2,3,0]
}

// ================== feat transpose (rows 0..3 only): ft[r][t] = feats[t*6+r] ==================
__global__ __launch_bounds__(256)
void feat_tr4(const float* __restrict__ feats, unsigned char* __restrict__ ws) {
  float* ft = (float*)(ws + FT4_OFF);
  int idx = blockIdx.x * 256 + threadIdx.x;           // 0 .. 4*SQ-1
  const int r = idx >> 16;                            // SQ = 65536
  const int t = idx & (SQ - 1);
  ft[(unsigned)r * SQ + (unsigned)t] = feats[(unsigned)t * 6u + (unsigned)r];
}

// ================== Tier-0 forward: 4-tag, quad_perm DPP (4-lane crossbar) ==================
// Tags 4 (START) and 5 (STOP) can never win any max (margin ~1e4): fv[0..3] is
// closed under p in {0..3} with bit-identical values. Step 0 handled specially.
__global__ __launch_bounds__(64, 1)
void viterbi_fwd4q(const float* __restrict__ trans, unsigned char* __restrict__ ws) {
  const int lane = threadIdx.x & 63;
  const int r = lane & 3;  // 16 quad-replicas of the 4-tag state

  // Probe quad_perm direction (HW/asm convention safe):
  // lane0 of [1,2,3,0] sees 1 -> lane r receives fv[(r+k)&3]
  int w = qperm1i(lane & 3);
  const int dir = (__builtin_amdgcn_readfirstlane(w) == 1) ? 1 : -1;

  // TT[k] pairs with the value arriving via quad rot k — fv of tag (r + dir*k) & 3
  float t0, t1, t2, t3;
  {
    float tmp[4];
#pragma unroll
    for (int k = 0; k < 4; ++k) {
      int p = (r + dir * k) & 3;
      tmp[k] = trans[r * 6 + p];
    }
    t0 = tmp[0]; t1 = tmp[1]; t2 = tmp[2]; t3 = tmp[3];
  }

  const float* fp = (const float*)(ws + FT4_OFF) + (unsigned)r * SQ;
  // Special step u=0: fl(0 + T[r,4]) = T[r,4] exact, then + f0[r]
  float nfv = trans[r * 6 + 4] + fp[0];
  unsigned voff = TR4_OFF + (unsigned)lane * 16u;

  // One step: 7 insts, 3 quad_perm DPP-adds. Bit-identical operand order to reference.
  auto step = [&](float ft_, float nin) -> float {
    float s0, s1, s2, s3, out;
    asm("v_add_f32 %[s0], %[nfv], %[t0]\n\t"
        "v_add_f32_dpp %[s1], %[nfv], %[t1] quad_perm:[1,2,3,0] row_mask:0xf bank_mask:0xf\n\t"
        "v_add_f32_dpp %[s2], %[nfv], %[t2] quad_perm:[2,3,0,1] row_mask:0xf bank_mask:0xf\n\t"
        "v_add_f32_dpp %[s3], %[nfv], %[t3] quad_perm:[3,0,1,2] row_mask:0xf bank_mask:0xf\n\t"
        "v_max3_f32 %[s0], %[s0], %[s1], %[s2]\n\t"
        "v_max_f32 %[s0], %[s0], %[s3]\n\t"
        "v_add_f32 %[out], %[s0], %[ft]"
        : [s0] "=&v"(s0), [s1] "=&v"(s1), [s2] "=&v"(s2), [s3] "=&v"(s3),
          [out] "=v"(out)
        : [nfv] "v"(nin), [t0] "v"(t0), [t1] "v"(t1), [t2] "v"(t2), [t3] "v"(t3),
          [ft] "v"(ft_));
    return out;
  };

  // Batch 0 (rec 0): slot0 = special fv1; steps u=1,2,3
  {
    float4 f = *(const float4*)(fp + 0);
    float b0 = nfv;
    float b1 = step(f.y, b0);
    float b2 = step(f.z, b1);
    float b3 = step(f.w, b2);
    nfv = b3;
    if (lane < 4) *(float4*)(ws + voff) = make_float4(b0, b1, b2, b3);
    voff += 64u;
  }
  // Main: batches b=1..16376 in 2047 blocks of 8, 32-step prefetch
  float4 fq[8];
#pragma unroll
  for (int i = 0; i < 8; ++i) fq[i] = *(const float4*)(fp + 4 + i * 4);
  for (int blk = 0; blk < 2047; ++blk) {
    const float* nextp = fp + 4 + (blk * 8 + 8) * 4;
#pragma unroll
    for (int i = 0; i < 8; ++i) {
      float4 f = fq[i];
      float b0 = step(f.x, nfv);
      float b1 = step(f.y, b0);
      float b2 = step(f.z, b1);
      float b3 = step(f.w, b2);
      nfv = b3;
      fq[i] = *(const float4*)(nextp + i * 4);  // overrun at end is benign (in-ws)
      if (lane < 4) *(float4*)(ws + voff) = make_float4(b0, b1, b2, b3);
      voff += 64u;
    }
  }
  // Tail: batches 16377..16383 (steps up to u=65535), direct loads
#pragma unroll
  for (int i = 0; i < 7; ++i) {
    float4 f = *(const float4*)(fp + (16377 + i) * 4);
    float b0 = step(f.x, nfv);
    float b1 = step(f.y, b0);
    float b2 = step(f.z, b1);
    float b3 = step(f.w, b2);
    nfv = b3;
    if (lane < 4) *(float4*)(ws + voff) = make_float4(b0, b1, b2, b3);
    voff += 64u;
  }
}

// ================== Parallel 4-tag backpointer extraction (bit-exact recompute) ==================
__global__ __launch_bounds__(256)
void bp4_kernel(const float* __restrict__ trans, unsigned char* __restrict__ ws) {
  const int t = blockIdx.x * 256 + threadIdx.x;
  unsigned acc = 0;
  if (t > 0) {
    const int u = t - 1;  // trace[u] = fv after feat row u; layout [u/4][tag][slot]
    const float* f = (const float*)(ws + TR4_OFF) + (unsigned)(u >> 2) * 16u + (unsigned)(u & 3);
    float fv0 = f[0], fv1 = f[4], fv2 = f[8], fv3 = f[12];
#pragma unroll
    for (int n = 0; n < 4; ++n) {
      float s0 = fv0 + trans[n * 6 + 0];
      float s1 = fv1 + trans[n * 6 + 1];
      float s2 = fv2 + trans[n * 6 + 2];
      float s3 = fv3 + trans[n * 6 + 3];
      float m = fmaxf(fmaxf(s0, s1), fmaxf(s2, s3));
      int idx = 3;
      idx = (s2 >= m) ? 2 : idx;
      idx = (s1 >= m) ? 1 : idx;
      idx = (s0 >= m) ? 0 : idx;  // numpy first-index tie rule; p=4,5 can't win/tie
      acc |= (unsigned)idx << (8 * n);
    }
  }
  ((unsigned*)(ws + BP4_OFF))[t] = acc;  // bp[0] never used by backtrack
}

// ================== Backtrack (4-tag, u32 bp words) ==================
__global__ __launch_bounds__(64, 1)
void bt_maps4(unsigned char* __restrict__ ws) {
  const int s = blockIdx.x;
  const int lane = threadIdx.x;
  int x = lane & 3;
  const unsigned* g = (const unsigned*)(ws + BP4_OFF);
  const int lo = s * BSEG + 1;
  const int hi = (s == NSEG - 1) ? (SQ - 1) : (s + 1) * BSEG;
#pragma unroll 8
  for (int j = hi; j >= lo; --j) {
    unsigned w = g[j];
    x = (int)((w >> (x * 8)) & 0xffu);
  }
  if (lane < 4) ws[B4_MAPS + (unsigned)s * 8u + (unsigned)lane] = (unsigned char)x;
}

__global__ __launch_bounds__(64, 1)
void bt_chain4(const float* __restrict__ trans, float* __restrict__ out,
               unsigned char* __restrict__ ws) {
  __shared__ unsigned char ml[NSEG * 8];
  const unsigned* src = (const unsigned*)(ws + B4_MAPS);
  unsigned* dstw = (unsigned*)ml;
  for (int i = threadIdx.x; i < NSEG * 2; i += 64) dstw[i] = src[i];
  __syncthreads();
  if (threadIdx.x == 0) {
    // terminal: fv[S-1] + trans[STOP]; tags 4,5 lose by ~1e4, argmax over 0..3
    const float* f = (const float*)(ws + TR4_OFF) + 16383u * 16u + 3u;
    float bm = f[0] + trans[30]; int bi = 0;
    float tv;
    tv = f[4]  + trans[31]; if (tv > bm) { bm = tv; bi = 1; }
    tv = f[8]  + trans[32]; if (tv > bm) { bm = tv; bi = 2; }
    tv = f[12] + trans[33]; if (tv > bm) { bm = tv; bi = 3; }
    out[0] = bm;
    *(unsigned*)(ws + B4_BEST) = (unsigned)bi;
    int x = bi;
    for (int s = NSEG - 1; s >= 1; --s) {
      x = ml[s * 8 + x];
      ws[B4_E + (unsigned)s] = (unsigned char)x;
    }
  }
}

__global__ __launch_bounds__(64, 1)
void bt_emit4(const unsigned char* __restrict__ ws, float* __restrict__ out) {
  const int s = blockIdx.x;
  if (threadIdx.x != 0) return;
  const unsigned* g = (const unsigned*)(ws + BP4_OFF);
  int x, hi;
  const int lo = s * BSEG + 1;
  if (s == NSEG - 1) {
    x = (int)*(const unsigned*)(ws + B4_BEST);
    out[1 + (SQ - 1)] = (float)x;
    hi = SQ - 1;
  } else {
    x = ws[B4_E + (unsigned)(s + 1)];
    hi = (s + 1) * BSEG;
  }
#pragma unroll 8
  for (int j = hi; j >= lo; --j) {
    unsigned w = g[j];
    x = (int)((w >> (x * 8)) & 0xffu);
    out[j] = (float)x;
  }
}

// ================== Tier-3 forward (fallback, full 6-tag) ==================
__global__ __launch_bounds__(64, 1)
void viterbi_fwd_old(const float* __restrict__ feats, const float* __restrict__ trans,
                     float* __restrict__ out, unsigned char* __restrict__ ws) {
  const int lane = threadIdx.x;
  if (lane >= 6) return;
  const float T0 = trans[lane * 6 + 0], T1 = trans[lane * 6 + 1], T2 = trans[lane * 6 + 2],
              T3 = trans[lane * 6 + 3], T4 = trans[lane * 6 + 4], T5 = trans[lane * 6 + 5];
  float fv0 = NEGV, fv1 = NEGV, fv2 = NEGV, fv3 = NEGV, fv4 = 0.0f, fv5 = NEGV;
  unsigned char* bpb = ws + OBP_OFF + lane;
  const float* fp = feats + lane;
  float fq[16];
#pragma unroll
  for (int i = 0; i < 16; ++i) fq[i] = fp[i * 6];
  auto step = [&](float ft, int tt) {
    float sc0 = fv0 + T0, sc1 = fv1 + T1, sc2 = fv2 + T2;
    float sc3 = fv3 + T3, sc4 = fv4 + T4, sc5 = fv5 + T5;
    float m = fmaxf(fmaxf(fmaxf(sc0, sc1), sc2), fmaxf(fmaxf(sc3, sc4), sc5));
    int idx = 5;
    idx = (sc4 >= m) ? 4 : idx;
    idx = (sc3 >= m) ? 3 : idx;
    idx = (sc2 >= m) ? 2 : idx;
    idx = (sc1 >= m) ? 1 : idx;
    idx = (sc0 >= m) ? 0 : idx;
    bpb[(unsigned)tt * 8u] = (unsigned char)idx;
    float nfv = m + ft;
    fv0 = rl(nfv, 0); fv1 = rl(nfv, 1); fv2 = rl(nfv, 2);
    fv3 = rl(nfv, 3); fv4 = rl(nfv, 4); fv5 = rl(nfv, 5);
  };
  for (int blk = 0; blk < SQ / 16 - 1; ++blk) {
    const int t = blk * 16;
#pragma unroll
    for (int i = 0; i < 16; ++i) { step(fq[i], t + i); fq[i] = fp[(t + i + 16) * 6]; }
  }
  { const int t = SQ - 16;
#pragma unroll
    for (int i = 0; i < 16; ++i) step(fq[i], t + i); }
  const float q0 = trans[30], q1 = trans[31], q2 = trans[32],
              q3 = trans[33], q4 = trans[34], q5 = trans[35];
  float tv0 = fv0 + q0, tv1 = fv1 + q1, tv2 = fv2 + q2;
  float tv3 = fv3 + q3, tv4 = fv4 + q4, tv5 = fv5 + q5;
  float bm = tv0; int bi = 0;
  if (tv1 > bm) { bm = tv1; bi = 1; }
  if (tv2 > bm) { bm = tv2; bi = 2; }
  if (tv3 > bm) { bm = tv3; bi = 3; }
  if (tv4 > bm) { bm = tv4; bi = 4; }
  if (tv5 > bm) { bm = tv5; bi = 5; }
  if (lane == 0) { out[0] = bm; *(unsigned*)(ws + OBEST_OFF) = (unsigned)bi; }
}

__global__ __launch_bounds__(64, 1)
void bt_maps_o(unsigned char* __restrict__ ws) {
  const int s = blockIdx.x;
  const int lane = threadIdx.x;
  int x = lane < 6 ? lane : 5;
  const unsigned long long* g = (const unsigned long long*)(ws + OBP_OFF);
  const int lo = s * BSEG + 1;
  const int hi = (s == NSEG - 1) ? (SQ - 1) : (s + 1) * BSEG;
#pragma unroll 8
  for (int j = hi; j >= lo; --j) {
    unsigned long long w = g[j];
    x = (int)((w >> (x * 8)) & 7ull);
  }
  if (lane < 6) ws[OMAPS_OFF + (unsigned)s * 8u + (unsigned)lane] = (unsigned char)x;
}

__global__ __launch_bounds__(64, 1)
void bt_chain_o(unsigned char* __restrict__ ws) {
  __shared__ unsigned char ml[NSEG * 8];
  const unsigned* src = (const unsigned*)(ws + OMAPS_OFF);
  unsigned* dstw = (unsigned*)ml;
  for (int i = threadIdx.x; i < NSEG * 2; i += 64) dstw[i] = src[i];
  __syncthreads();
  if (threadIdx.x == 0) {
    int x = (int)*(const unsigned*)(ws + OBEST_OFF);
    for (int s = NSEG - 1; s >= 1; --s) {
      x = ml[s * 8 + x];
      ws[OE_OFF + (unsigned)s] = (unsigned char)x;
    }
  }
}

__global__ __launch_bounds__(64, 1)
void bt_emit_o(const unsigned char* __restrict__ ws, float* __restrict__ out) {
  const int s = blockIdx.x;
  if (threadIdx.x != 0) return;
  const unsigned long long* g = (const unsigned long long*)(ws + OBP_OFF);
  int x, hi;
  const int lo = s * BSEG + 1;
  if (s == NSEG - 1) {
    x = (int)*(const unsigned*)(ws + OBEST_OFF);
    out[1 + (SQ - 1)] = (float)x;
    hi = SQ - 1;
  } else {
    x = ws[OE_OFF + (unsigned)(s + 1)];
    hi = (s + 1) * BSEG;
  }
#pragma unroll 8
  for (int j = hi; j >= lo; --j) {
    unsigned long long w = g[j];
    x = (int)((w >> (x * 8)) & 7ull);
    out[j] = (float)x;
  }
}

extern "C" void kernel_launch(void* const* d_in, const int* in_sizes, int n_in,
                              void* d_out, int out_size, void* d_ws, size_t ws_size,
                              hipStream_t stream) {
  const float* feats = (const float*)d_in[0];
  const float* trans = (const float*)d_in[1];
  float* out = (float*)d_out;
  unsigned char* ws = (unsigned char*)d_ws;

  if (ws_size >= WS0) {
    feat_tr4<<<4 * SQ / 256, 256, 0, stream>>>(feats, ws);
    viterbi_fwd4q<<<1, 64, 0, stream>>>(trans, ws);
    bp4_kernel<<<NSEG, 256, 0, stream>>>(trans, ws);
    bt_maps4<<<NSEG, 64, 0, stream>>>(ws);
    bt_chain4<<<1, 64, 0, stream>>>(trans, out, ws);
    bt_emit4<<<NSEG, 64, 0, stream>>>(ws, out);
  } else {
    viterbi_fwd_old<<<1, 64, 0, stream>>>(feats, trans, out, ws);
    bt_maps_o<<<NSEG, 64, 0, stream>>>(ws);
    bt_chain_o<<<1, 64, 0, stream>>>(ws);
    bt_emit_o<<<NSEG, 64, 0, stream>>>(ws, out);
  }
}

// Round 11
// 1319.078 us; speedup vs baseline: 1.6568x; 1.0716x over previous
//
#include <hip/hip_runtime.h>

#define SQ 65536
#define BSEG 256
#define NSEG (SQ / BSEG)
#define NEGV (-10000.0f)

// ---- Tier-0 ws layout (4-tag reduced recursion, no feat transpose) ----
// TR4: [SQ/4][4 tags][4 slots] f32 = 1 MB ; BP4: SQ*4 = 256 KB
#define TR4_OFF   0u
#define BP4_OFF   ((unsigned)SQ * 16u)
#define B4_BEST   (BP4_OFF + (unsigned)SQ * 4u)
#define B4_MAPS   (B4_BEST + 32u)
#define B4_E      (B4_MAPS + (unsigned)NSEG * 8u)
#define WS0       ((size_t)(B4_E + NSEG + 64))

// ---- Tier-3 (old 6-tag single-kernel) ws layout ----
#define OBP_OFF   0u
#define OBEST_OFF ((unsigned)SQ * 8u)
#define OMAPS_OFF (OBEST_OFF + 32u)
#define OE_OFF    (OMAPS_OFF + (unsigned)NSEG * 8u)

__device__ __forceinline__ float rl(float v, int l) {
  return __int_as_float(__builtin_amdgcn_readlane(__float_as_int(v), l));
}
// quad_perm rotate-by-1 probe helper: [1,2,3,0]
__device__ __forceinline__ int qperm1i(int v) {
  return __builtin_amdgcn_update_dpp(0, v, 0x39, 0xF, 0xF, true);
}

// ================== Tier-0 forward: 4-tag, quad_perm DPP, direct feat loads ==================
// Tags 4 (START) and 5 (STOP) can never win any max (margin ~1e4): fv[0..3] is
// closed under p in {0..3} with bit-identical values. Step 0 handled specially
// (START dominates): fv1[n] = fl(T[n,4] + f0[n]).
// Chain floor: dpp-add(33) + max3(6) + max(6) + add(6) ~= 51 cy/step (measured 50.7).
__global__ __launch_bounds__(64, 1)
void viterbi_fwd4d(const float* __restrict__ feats, const float* __restrict__ trans,
                   unsigned char* __restrict__ ws) {
  const int lane = threadIdx.x & 63;
  const int r = lane & 3;  // 16 quad-replicas of the 4-tag state

  // Probe quad_perm direction (HW/asm convention safe)
  int w = qperm1i(lane & 3);
  const int dir = (__builtin_amdgcn_readfirstlane(w) == 1) ? 1 : -1;

  // TT[k] pairs with the value arriving via quad rot k — fv of tag (r + dir*k) & 3
  float t0, t1, t2, t3;
  {
    float tmp[4];
#pragma unroll
    for (int k = 0; k < 4; ++k) {
      int p = (r + dir * k) & 3;
      tmp[k] = trans[r * 6 + p];
    }
    t0 = tmp[0]; t1 = tmp[1]; t2 = tmp[2]; t3 = tmp[3];
  }

  const float* fb = feats + r;  // lane's feat column, stride 6
  // Special step u=0: fl(0 + T[r,4]) = T[r,4] exact, then + f0[r]
  float nfv = trans[r * 6 + 4] + fb[0];
  unsigned voff = TR4_OFF + (unsigned)lane * 16u;

  // One step: 7 insts, 3 quad_perm DPP-adds. Bit-identical operand order to reference.
  auto step = [&](float ft_, float nin) -> float {
    float s0, s1, s2, s3, out;
    asm("v_add_f32 %[s0], %[nfv], %[t0]\n\t"
        "v_add_f32_dpp %[s1], %[nfv], %[t1] quad_perm:[1,2,3,0] row_mask:0xf bank_mask:0xf\n\t"
        "v_add_f32_dpp %[s2], %[nfv], %[t2] quad_perm:[2,3,0,1] row_mask:0xf bank_mask:0xf\n\t"
        "v_add_f32_dpp %[s3], %[nfv], %[t3] quad_perm:[3,0,1,2] row_mask:0xf bank_mask:0xf\n\t"
        "v_max3_f32 %[s0], %[s0], %[s1], %[s2]\n\t"
        "v_max_f32 %[s0], %[s0], %[s3]\n\t"
        "v_add_f32 %[out], %[s0], %[ft]"
        : [s0] "=&v"(s0), [s1] "=&v"(s1), [s2] "=&v"(s2), [s3] "=&v"(s3),
          [out] "=v"(out)
        : [nfv] "v"(nin), [t0] "v"(t0), [t1] "v"(t1), [t2] "v"(t2), [t3] "v"(t3),
          [ft] "v"(ft_));
    return out;
  };

  // Load a 4-step feat batch directly from feats (offsets 0/24/48/72 bytes)
  auto ldb = [&](int batch) -> float4 {
    const float* p = fb + (unsigned)batch * 24u;  // 4 steps * stride 6
    return make_float4(p[0], p[6], p[12], p[18]);
  };

  // Batch 0: slot0 = special fv1; steps u=1,2,3
  {
    float4 f = ldb(0);
    float b0 = nfv;
    float b1 = step(f.y, b0);
    float b2 = step(f.z, b1);
    float b3 = step(f.w, b2);
    nfv = b3;
    if (lane < 4) *(float4*)(ws + voff) = make_float4(b0, b1, b2, b3);
    voff += 64u;
  }
  // Main: batches 1..16368 in 2046 blocks of 8, 32-step prefetch.
  // Prefetch max batch = 9 + 2045*8 + 7 = 16376 <= 16383: never reads past feats.
  float4 fq[8];
#pragma unroll
  for (int i = 0; i < 8; ++i) fq[i] = ldb(1 + i);
  for (int blk = 0; blk < 2046; ++blk) {
#pragma unroll
    for (int i = 0; i < 8; ++i) {
      float4 f = fq[i];
      float b0 = step(f.x, nfv);
      float b1 = step(f.y, b0);
      float b2 = step(f.z, b1);
      float b3 = step(f.w, b2);
      nfv = b3;
      fq[i] = ldb(9 + blk * 8 + i);
      if (lane < 4) *(float4*)(ws + voff) = make_float4(b0, b1, b2, b3);
      voff += 64u;
    }
  }
  // Tail A: 8 batches already in fq (16369..16376), no further prefetch
#pragma unroll
  for (int i = 0; i < 8; ++i) {
    float4 f = fq[i];
    float b0 = step(f.x, nfv);
    float b1 = step(f.y, b0);
    float b2 = step(f.z, b1);
    float b3 = step(f.w, b2);
    nfv = b3;
    if (lane < 4) *(float4*)(ws + voff) = make_float4(b0, b1, b2, b3);
    voff += 64u;
  }
  // Tail B: batches 16377..16383, direct loads (max t = 65535, in bounds)
#pragma unroll
  for (int i = 0; i < 7; ++i) {
    float4 f = ldb(16377 + i);
    float b0 = step(f.x, nfv);
    float b1 = step(f.y, b0);
    float b2 = step(f.z, b1);
    float b3 = step(f.w, b2);
    nfv = b3;
    if (lane < 4) *(float4*)(ws + voff) = make_float4(b0, b1, b2, b3);
    voff += 64u;
  }
}

// ================== Parallel 4-tag backpointer extraction (bit-exact recompute) ==================
__global__ __launch_bounds__(256)
void bp4_kernel(const float* __restrict__ trans, unsigned char* __restrict__ ws) {
  const int t = blockIdx.x * 256 + threadIdx.x;
  unsigned acc = 0;
  if (t > 0) {
    const int u = t - 1;  // trace[u] = fv after feat row u; layout [u/4][tag][slot]
    const float* f = (const float*)(ws + TR4_OFF) + (unsigned)(u >> 2) * 16u + (unsigned)(u & 3);
    float fv0 = f[0], fv1 = f[4], fv2 = f[8], fv3 = f[12];
#pragma unroll
    for (int n = 0; n < 4; ++n) {
      float s0 = fv0 + trans[n * 6 + 0];
      float s1 = fv1 + trans[n * 6 + 1];
      float s2 = fv2 + trans[n * 6 + 2];
      float s3 = fv3 + trans[n * 6 + 3];
      float m = fmaxf(fmaxf(s0, s1), fmaxf(s2, s3));
      int idx = 3;
      idx = (s2 >= m) ? 2 : idx;
      idx = (s1 >= m) ? 1 : idx;
      idx = (s0 >= m) ? 0 : idx;  // numpy first-index tie rule; p=4,5 can't win/tie
      acc |= (unsigned)idx << (8 * n);
    }
  }
  ((unsigned*)(ws + BP4_OFF))[t] = acc;  // bp[0] never used by backtrack
}

// ================== Backtrack (4-tag, u32 bp words) ==================
__global__ __launch_bounds__(64, 1)
void bt_maps4(unsigned char* __restrict__ ws) {
  const int s = blockIdx.x;
  const int lane = threadIdx.x;
  int x = lane & 3;
  const unsigned* g = (const unsigned*)(ws + BP4_OFF);
  const int lo = s * BSEG + 1;
  const int hi = (s == NSEG - 1) ? (SQ - 1) : (s + 1) * BSEG;
#pragma unroll 8
  for (int j = hi; j >= lo; --j) {
    unsigned w = g[j];
    x = (int)((w >> (x * 8)) & 0xffu);
  }
  if (lane < 4) ws[B4_MAPS + (unsigned)s * 8u + (unsigned)lane] = (unsigned char)x;
}

__global__ __launch_bounds__(64, 1)
void bt_chain4(const float* __restrict__ trans, float* __restrict__ out,
               unsigned char* __restrict__ ws) {
  __shared__ unsigned char ml[NSEG * 8];
  const unsigned* src = (const unsigned*)(ws + B4_MAPS);
  unsigned* dstw = (unsigned*)ml;
  for (int i = threadIdx.x; i < NSEG * 2; i += 64) dstw[i] = src[i];
  __syncthreads();
  if (threadIdx.x == 0) {
    // terminal: fv[S-1] + trans[STOP]; tags 4,5 lose by ~1e4, argmax over 0..3
    const float* f = (const float*)(ws + TR4_OFF) + 16383u * 16u + 3u;
    float bm = f[0] + trans[30]; int bi = 0;
    float tv;
    tv = f[4]  + trans[31]; if (tv > bm) { bm = tv; bi = 1; }
    tv = f[8]  + trans[32]; if (tv > bm) { bm = tv; bi = 2; }
    tv = f[12] + trans[33]; if (tv > bm) { bm = tv; bi = 3; }
    out[0] = bm;
    *(unsigned*)(ws + B4_BEST) = (unsigned)bi;
    int x = bi;
    for (int s = NSEG - 1; s >= 1; --s) {
      x = ml[s * 8 + x];
      ws[B4_E + (unsigned)s] = (unsigned char)x;
    }
  }
}

__global__ __launch_bounds__(64, 1)
void bt_emit4(const unsigned char* __restrict__ ws, float* __restrict__ out) {
  const int s = blockIdx.x;
  if (threadIdx.x != 0) return;
  const unsigned* g = (const unsigned*)(ws + BP4_OFF);
  int x, hi;
  const int lo = s * BSEG + 1;
  if (s == NSEG - 1) {
    x = (int)*(const unsigned*)(ws + B4_BEST);
    out[1 + (SQ - 1)] = (float)x;
    hi = SQ - 1;
  } else {
    x = ws[B4_E + (unsigned)(s + 1)];
    hi = (s + 1) * BSEG;
  }
#pragma unroll 8
  for (int j = hi; j >= lo; --j) {
    unsigned w = g[j];
    x = (int)((w >> (x * 8)) & 0xffu);
    out[j] = (float)x;
  }
}

// ================== Tier-3 forward (fallback, full 6-tag) ==================
__global__ __launch_bounds__(64, 1)
void viterbi_fwd_old(const float* __restrict__ feats, const float* __restrict__ trans,
                     float* __restrict__ out, unsigned char* __restrict__ ws) {
  const int lane = threadIdx.x;
  if (lane >= 6) return;
  const float T0 = trans[lane * 6 + 0], T1 = trans[lane * 6 + 1], T2 = trans[lane * 6 + 2],
              T3 = trans[lane * 6 + 3], T4 = trans[lane * 6 + 4], T5 = trans[lane * 6 + 5];
  float fv0 = NEGV, fv1 = NEGV, fv2 = NEGV, fv3 = NEGV, fv4 = 0.0f, fv5 = NEGV;
  unsigned char* bpb = ws + OBP_OFF + lane;
  const float* fp = feats + lane;
  float fq[16];
#pragma unroll
  for (int i = 0; i < 16; ++i) fq[i] = fp[i * 6];
  auto step = [&](float ft, int tt) {
    float sc0 = fv0 + T0, sc1 = fv1 + T1, sc2 = fv2 + T2;
    float sc3 = fv3 + T3, sc4 = fv4 + T4, sc5 = fv5 + T5;
    float m = fmaxf(fmaxf(fmaxf(sc0, sc1), sc2), fmaxf(fmaxf(sc3, sc4), sc5));
    int idx = 5;
    idx = (sc4 >= m) ? 4 : idx;
    idx = (sc3 >= m) ? 3 : idx;
    idx = (sc2 >= m) ? 2 : idx;
    idx = (sc1 >= m) ? 1 : idx;
    idx = (sc0 >= m) ? 0 : idx;
    bpb[(unsigned)tt * 8u] = (unsigned char)idx;
    float nfv = m + ft;
    fv0 = rl(nfv, 0); fv1 = rl(nfv, 1); fv2 = rl(nfv, 2);
    fv3 = rl(nfv, 3); fv4 = rl(nfv, 4); fv5 = rl(nfv, 5);
  };
  for (int blk = 0; blk < SQ / 16 - 1; ++blk) {
    const int t = blk * 16;
#pragma unroll
    for (int i = 0; i < 16; ++i) { step(fq[i], t + i); fq[i] = fp[(t + i + 16) * 6]; }
  }
  { const int t = SQ - 16;
#pragma unroll
    for (int i = 0; i < 16; ++i) step(fq[i], t + i); }
  const float q0 = trans[30], q1 = trans[31], q2 = trans[32],
              q3 = trans[33], q4 = trans[34], q5 = trans[35];
  float tv0 = fv0 + q0, tv1 = fv1 + q1, tv2 = fv2 + q2;
  float tv3 = fv3 + q3, tv4 = fv4 + q4, tv5 = fv5 + q5;
  float bm = tv0; int bi = 0;
  if (tv1 > bm) { bm = tv1; bi = 1; }
  if (tv2 > bm) { bm = tv2; bi = 2; }
  if (tv3 > bm) { bm = tv3; bi = 3; }
  if (tv4 > bm) { bm = tv4; bi = 4; }
  if (tv5 > bm) { bm = tv5; bi = 5; }
  if (lane == 0) { out[0] = bm; *(unsigned*)(ws + OBEST_OFF) = (unsigned)bi; }
}

__global__ __launch_bounds__(64, 1)
void bt_maps_o(unsigned char* __restrict__ ws) {
  const int s = blockIdx.x;
  const int lane = threadIdx.x;
  int x = lane < 6 ? lane : 5;
  const unsigned long long* g = (const unsigned long long*)(ws + OBP_OFF);
  const int lo = s * BSEG + 1;
  const int hi = (s == NSEG - 1) ? (SQ - 1) : (s + 1) * BSEG;
#pragma unroll 8
  for (int j = hi; j >= lo; --j) {
    unsigned long long w = g[j];
    x = (int)((w >> (x * 8)) & 7ull);
  }
  if (lane < 6) ws[OMAPS_OFF + (unsigned)s * 8u + (unsigned)lane] = (unsigned char)x;
}

__global__ __launch_bounds__(64, 1)
void bt_chain_o(unsigned char* __restrict__ ws) {
  __shared__ unsigned char ml[NSEG * 8];
  const unsigned* src = (const unsigned*)(ws + OMAPS_OFF);
  unsigned* dstw = (unsigned*)ml;
  for (int i = threadIdx.x; i < NSEG * 2; i += 64) dstw[i] = src[i];
  __syncthreads();
  if (threadIdx.x == 0) {
    int x = (int)*(const unsigned*)(ws + OBEST_OFF);
    for (int s = NSEG - 1; s >= 1; --s) {
      x = ml[s * 8 + x];
      ws[OE_OFF + (unsigned)s] = (unsigned char)x;
    }
  }
}

__global__ __launch_bounds__(64, 1)
void bt_emit_o(const unsigned char* __restrict__ ws, float* __restrict__ out) {
  const int s = blockIdx.x;
  if (threadIdx.x != 0) return;
  const unsigned long long* g = (const unsigned long long*)(ws + OBP_OFF);
  int x, hi;
  const int lo = s * BSEG + 1;
  if (s == NSEG - 1) {
    x = (int)*(const unsigned*)(ws + OBEST_OFF);
    out[1 + (SQ - 1)] = (float)x;
    hi = SQ - 1;
  } else {
    x = ws[OE_OFF + (unsigned)(s + 1)];
    hi = (s + 1) * BSEG;
  }
#pragma unroll 8
  for (int j = hi; j >= lo; --j) {
    unsigned long long w = g[j];
    x = (int)((w >> (x * 8)) & 7ull);
    out[j] = (float)x;
  }
}

extern "C" void kernel_launch(void* const* d_in, const int* in_sizes, int n_in,
                              void* d_out, int out_size, void* d_ws, size_t ws_size,
                              hipStream_t stream) {
  const float* feats = (const float*)d_in[0];
  const float* trans = (const float*)d_in[1];
  float* out = (float*)d_out;
  unsigned char* ws = (unsigned char*)d_ws;

  if (ws_size >= WS0) {
    viterbi_fwd4d<<<1, 64, 0, stream>>>(feats, trans, ws);
    bp4_kernel<<<NSEG, 256, 0, stream>>>(trans, ws);
    bt_maps4<<<NSEG, 64, 0, stream>>>(ws);
    bt_chain4<<<1, 64, 0, stream>>>(trans, out, ws);
    bt_emit4<<<NSEG, 64, 0, stream>>>(ws, out);
  } else {
    viterbi_fwd_old<<<1, 64, 0, stream>>>(feats, trans, out, ws);
    bt_maps_o<<<NSEG, 64, 0, stream>>>(ws);
    bt_chain_o<<<1, 64, 0, stream>>>(ws);
    bt_emit_o<<<NSEG, 64, 0, stream>>>(ws, out);
  }
}